// Round 1
// baseline (136.331 us; speedup 1.0000x reference)
//
#include <hip/hip_runtime.h>

// Problem sizes
#define LN   512      // FFT length
#define FB   257      // rfft bins = L/2+1
#define CB   128      // channels
#define NROW 2048     // B*C rows

// ---------------------------------------------------------------------------
// Kernel 0: twiddle table tw[j] = exp(-2*pi*i*j/512), j=0..255, in double.
// ---------------------------------------------------------------------------
__global__ void k_twiddle(double2* __restrict__ tw) {
    int j = threadIdx.x;  // 256 threads
    const double PI = 3.14159265358979323846264338327950288;
    double theta = -2.0 * PI * (double)j / 512.0;
    double s, c;
    sincos(theta, &s, &c);
    tw[j] = make_double2(c, s);
}

// ---------------------------------------------------------------------------
// Kernel 1: per-row 512-point complex FFT (imag=0), radix-2 DIT in LDS,
// output xf[row][k] = |X_k| for k=0..256, all in double.
// One block (64 threads = 1 wave) per row.
// ---------------------------------------------------------------------------
__global__ void k_fft_mag(const float* __restrict__ x,
                          const double2* __restrict__ twg,
                          double* __restrict__ xf) {
    __shared__ double2 a[LN];
    __shared__ double2 tw[256];
    const int row  = blockIdx.x;
    const int lane = threadIdx.x;  // 0..63

    // stage twiddles into LDS
    for (int t = lane; t < 256; t += 64) tw[t] = twg[t];

    // load input, bit-reversed placement (DIT: bit-rev in -> natural out)
    const float* xr = x + (size_t)row * LN;
    #pragma unroll
    for (int q = 0; q < 8; ++q) {
        int n = lane + 64 * q;
        int r = (int)(__brev((unsigned)n) >> 23);  // 9-bit reverse
        a[r] = make_double2((double)xr[n], 0.0);
    }
    __syncthreads();

    // 9 radix-2 stages, 256 butterflies each, 4 per lane
    for (int s = 1; s <= 9; ++s) {
        const int half   = 1 << (s - 1);
        const int tshift = 9 - s;
        #pragma unroll
        for (int t = lane; t < 256; t += 64) {
            int k   = t & (half - 1);
            int grp = t >> (s - 1);
            int p0  = (grp << s) + k;
            int p1  = p0 + half;
            double2 w = tw[k << tshift];
            double2 u = a[p0];
            double2 v = a[p1];
            double vr = v.x * w.x - v.y * w.y;
            double vi = v.x * w.y + v.y * w.x;
            a[p0] = make_double2(u.x + vr, u.y + vi);
            a[p1] = make_double2(u.x - vr, u.y - vi);
        }
        __syncthreads();
    }

    // magnitudes of bins 0..256
    for (int k = lane; k < FB; k += 64) {
        double re = a[k].x, im = a[k].y;
        xf[(size_t)row * FB + k] = sqrt(re * re + im * im);
    }
}

// ---------------------------------------------------------------------------
// Kernel 2: Z[row][g] = sum_f xf[row][f] * A[g][f]   (f64 accumulate)
// One block (256 threads) per row; thread t handles g = t (+256).
// ---------------------------------------------------------------------------
__global__ void k_zmat(const double* __restrict__ xf,
                       const float* __restrict__ A,
                       double* __restrict__ Z) {
    __shared__ double sxf[FB];
    const int row = blockIdx.x;
    const int t   = threadIdx.x;  // 0..255
    for (int f = t; f < FB; f += 256) sxf[f] = xf[(size_t)row * FB + f];
    __syncthreads();
    for (int g = t; g < FB; g += 256) {
        const float* Ar = A + (size_t)g * FB;
        double acc0 = 0.0, acc1 = 0.0;
        int f = 0;
        for (; f + 1 < FB; f += 2) {
            acc0 += sxf[f]     * (double)Ar[f];
            acc1 += sxf[f + 1] * (double)Ar[f + 1];
        }
        acc0 += sxf[FB - 1] * (double)Ar[FB - 1];
        Z[(size_t)row * FB + g] = acc0 + acc1;
    }
}

// ---------------------------------------------------------------------------
// Kernel 3: per (b,i): dist to all j, row max of 1/(dist+3e-8) (diag zeroed),
// then p -> logits -> gumbel comparison -> binary mask.
// One block (128 threads) per (b,i); thread = j.
// ---------------------------------------------------------------------------
__global__ void k_mask(const double* __restrict__ Z,
                       const float* __restrict__ gu,
                       float* __restrict__ out) {
    __shared__ double zi[FB];
    __shared__ double red[CB];
    const int bi = blockIdx.x;        // b*128 + i
    const int i  = bi & (CB - 1);
    const int b  = bi >> 7;
    const int j  = threadIdx.x;       // 0..127

    const double* Zb = Z + (size_t)b * CB * FB;
    for (int f = j; f < FB; f += CB) zi[f] = Zb[(size_t)i * FB + f];
    __syncthreads();

    // dist[b][i][j] = sum_g (Z[b][j][g] - Z[b][i][g])^2
    const double* Zj = Zb + (size_t)j * FB;
    double d0 = 0.0, d1 = 0.0;
    int g = 0;
    for (; g + 1 < FB; g += 2) {
        double e0 = Zj[g]     - zi[g];
        double e1 = Zj[g + 1] - zi[g + 1];
        d0 += e0 * e0;
        d1 += e1 * e1;
    }
    {
        double e0 = Zj[FB - 1] - zi[FB - 1];
        d0 += e0 * e0;
    }
    double dist = d0 + d1;

    double ed = 1.0 / (dist + 3e-8);
    if (j == i) ed = 0.0;   // * (1 - eye)

    // block max reduction over 128 values
    red[j] = ed;
    __syncthreads();
    #pragma unroll
    for (int off = 64; off >= 1; off >>= 1) {
        if (j < off) red[j] = fmax(red[j], red[j + off]);
        __syncthreads();
    }
    double emax = red[0];

    double p = ed / (emax + 1e-8);
    if (j == i) p = p + 1.0;          // + eye
    p *= 0.99;
    double logits = log(p + 1e-8) - log((1.0 - p) + 1e-8);

    float2 u2 = ((const float2*)gu)[(size_t)bi * CB + j];
    double g0 = -log(-log((double)u2.x + 1e-20) + 1e-20);
    double g1 = -log(-log((double)u2.y + 1e-20) + 1e-20);

    // forward value of straight-through sample = one_hot(argmax(logits_pair+g))
    // argmax ties -> index 0 -> mask 1, so use >=
    double a0 = logits + g0;
    double a1 = -logits + g1;
    out[(size_t)bi * CB + j] = (a0 >= a1) ? 1.0f : 0.0f;
}

// ---------------------------------------------------------------------------
extern "C" void kernel_launch(void* const* d_in, const int* in_sizes, int n_in,
                              void* d_out, int out_size, void* d_ws, size_t ws_size,
                              hipStream_t stream) {
    const float* x  = (const float*)d_in[0];   // (16,128,512)
    const float* A  = (const float*)d_in[1];   // (257,257)
    const float* gu = (const float*)d_in[2];   // (16,128,128,2)
    float* out = (float*)d_out;                // (16,1,128,128)

    char* ws = (char*)d_ws;
    double2* tw = (double2*)ws;                                  // 4 KB
    double*  xf = (double*)(ws + 4096);                          // 2048*257*8 = 4.21 MB
    double*  Z  = (double*)(ws + 4096 + (size_t)NROW * FB * 8);  // 4.21 MB

    hipLaunchKernelGGL(k_twiddle, dim3(1),    dim3(256), 0, stream, tw);
    hipLaunchKernelGGL(k_fft_mag, dim3(NROW), dim3(64),  0, stream, x, tw, xf);
    hipLaunchKernelGGL(k_zmat,    dim3(NROW), dim3(256), 0, stream, xf, A, Z);
    hipLaunchKernelGGL(k_mask,    dim3(NROW), dim3(128), 0, stream, Z, gu, out);
}

// Round 2
// 117.133 us; speedup vs baseline: 1.1639x; 1.1639x over previous
//
#include <hip/hip_runtime.h>

// Problem sizes
#define LN   512      // FFT length
#define FB   257      // rfft bins = L/2+1
#define CB   128      // channels
#define NROW 2048     // B*C rows
#define RT   8        // rows per k_zmat block
#define TI   8        // i-rows per k_mask block

// ---------------------------------------------------------------------------
// Kernel 0a: twiddle table tw[j] = exp(-2*pi*i*j/512), j=0..255, double.
// ---------------------------------------------------------------------------
__global__ void k_twiddle(double2* __restrict__ tw) {
    int j = threadIdx.x;  // 256 threads
    const double PI = 3.14159265358979323846264338327950288;
    double theta = -2.0 * PI * (double)j / 512.0;
    double s, c;
    sincos(theta, &s, &c);
    tw[j] = make_double2(c, s);
}

// ---------------------------------------------------------------------------
// Kernel 0b: At[f][g] = A[g][f]  (f32 transpose so zmat loads are coalesced)
// ---------------------------------------------------------------------------
__global__ void k_transpose(const float* __restrict__ A, float* __restrict__ At) {
    int idx = blockIdx.x * 256 + threadIdx.x;
    if (idx < FB * FB) {
        int f = idx / FB;
        int g = idx - f * FB;
        At[idx] = A[g * FB + f];
    }
}

// ---------------------------------------------------------------------------
// Kernel 1: per-row 512-point complex FFT (imag=0), radix-2 DIT in LDS,
// output xf[row][k] = |X_k| for k=0..256, double. One wave per row.
// ---------------------------------------------------------------------------
__global__ void k_fft_mag(const float* __restrict__ x,
                          const double2* __restrict__ twg,
                          double* __restrict__ xf) {
    __shared__ double2 a[LN];
    __shared__ double2 tw[256];
    const int row  = blockIdx.x;
    const int lane = threadIdx.x;  // 0..63

    for (int t = lane; t < 256; t += 64) tw[t] = twg[t];

    const float* xr = x + (size_t)row * LN;
    #pragma unroll
    for (int q = 0; q < 8; ++q) {
        int n = lane + 64 * q;
        int r = (int)(__brev((unsigned)n) >> 23);  // 9-bit reverse
        a[r] = make_double2((double)xr[n], 0.0);
    }
    __syncthreads();

    for (int s = 1; s <= 9; ++s) {
        const int half   = 1 << (s - 1);
        const int tshift = 9 - s;
        #pragma unroll
        for (int t = lane; t < 256; t += 64) {
            int k   = t & (half - 1);
            int grp = t >> (s - 1);
            int p0  = (grp << s) + k;
            int p1  = p0 + half;
            double2 w = tw[k << tshift];
            double2 u = a[p0];
            double2 v = a[p1];
            double vr = v.x * w.x - v.y * w.y;
            double vi = v.x * w.y + v.y * w.x;
            a[p0] = make_double2(u.x + vr, u.y + vi);
            a[p1] = make_double2(u.x - vr, u.y - vi);
        }
        __syncthreads();
    }

    for (int k = lane; k < FB; k += 64) {
        double re = a[k].x, im = a[k].y;
        xf[(size_t)row * FB + k] = sqrt(re * re + im * im);
    }
}

// ---------------------------------------------------------------------------
// Kernel 2: Z[row][g] = sum_f xf[row][f] * A[g][f], 8 rows per block.
// Thread t = g (0..256 active of 320). Coalesced At[f][g] loads.
// Writes row-major Z and per-b transposed Zt[b][g][i].
// ---------------------------------------------------------------------------
__global__ __launch_bounds__(320)
void k_zmat(const double* __restrict__ xf,
            const float* __restrict__ At,
            double* __restrict__ Z,
            double* __restrict__ Zt) {
    __shared__ double sxf[RT][FB];
    const int r0 = blockIdx.x * RT;         // global row base (same b for all 8)
    const int t  = threadIdx.x;             // 0..319

    for (int idx = t; idx < RT * FB; idx += 320) {
        int r = idx / FB;
        int f = idx - r * FB;
        sxf[r][f] = xf[(size_t)(r0 + r) * FB + f];
    }
    __syncthreads();

    if (t < FB) {
        const int g = t;
        double acc[RT];
        #pragma unroll
        for (int r = 0; r < RT; ++r) acc[r] = 0.0;

        int f = 0;
        for (; f + 2 <= 256; f += 2) {
            double a0 = (double)At[(size_t)f * FB + g];
            double a1 = (double)At[(size_t)(f + 1) * FB + g];
            #pragma unroll
            for (int r = 0; r < RT; ++r) {
                acc[r] += sxf[r][f] * a0;
                acc[r] += sxf[r][f + 1] * a1;
            }
        }
        {   // f = 256 tail
            double a0 = (double)At[(size_t)256 * FB + g];
            #pragma unroll
            for (int r = 0; r < RT; ++r) acc[r] += sxf[r][256] * a0;
        }

        const int b  = r0 >> 7;
        const int i0 = r0 & (CB - 1);
        #pragma unroll
        for (int r = 0; r < RT; ++r) {
            Z[(size_t)(r0 + r) * FB + g] = acc[r];
            Zt[((size_t)b * FB + g) * CB + (i0 + r)] = acc[r];
        }
    }
}

// ---------------------------------------------------------------------------
// Kernel 3: per block: one b, 8 i-rows; thread j = 0..127.
// dist -> ed -> rowmax -> p -> logits -> gumbel compare -> binary mask.
// ---------------------------------------------------------------------------
__global__ __launch_bounds__(128)
void k_mask(const double* __restrict__ Z,
            const double* __restrict__ Zt,
            const float* __restrict__ gu,
            float* __restrict__ out) {
    __shared__ double zi[TI][FB];
    __shared__ double red[TI][CB];
    const int blk = blockIdx.x;             // 0..255
    const int b   = blk >> 4;               // 16 i-tiles per b
    const int i0  = (blk & 15) * TI;
    const int j   = threadIdx.x;            // 0..127

    // stage the 8 zi rows (coalesced from row-major Z)
    for (int idx = j; idx < TI * FB; idx += CB) {
        int r = idx / FB;
        int f = idx - r * FB;
        zi[r][f] = Z[((size_t)(b * CB + i0 + r)) * FB + f];
    }
    __syncthreads();

    const double* Ztb = Zt + (size_t)b * FB * CB;
    double acc[TI];
    #pragma unroll
    for (int r = 0; r < TI; ++r) acc[r] = 0.0;

    int g = 0;
    for (; g + 2 <= 256; g += 2) {
        double z0 = Ztb[(size_t)g * CB + j];
        double z1 = Ztb[(size_t)(g + 1) * CB + j];
        #pragma unroll
        for (int r = 0; r < TI; ++r) {
            double e0 = z0 - zi[r][g];
            acc[r] += e0 * e0;
            double e1 = z1 - zi[r][g + 1];
            acc[r] += e1 * e1;
        }
    }
    {   // g = 256 tail
        double z0 = Ztb[(size_t)256 * CB + j];
        #pragma unroll
        for (int r = 0; r < TI; ++r) {
            double e0 = z0 - zi[r][256];
            acc[r] += e0 * e0;
        }
    }

    double ed[TI];
    #pragma unroll
    for (int r = 0; r < TI; ++r) {
        ed[r] = 1.0 / (acc[r] + 3e-8);
        if (i0 + r == j) ed[r] = 0.0;      // * (1 - eye)
        red[r][j] = ed[r];
    }
    __syncthreads();

    #pragma unroll
    for (int off = 64; off >= 1; off >>= 1) {
        if (j < off) {
            #pragma unroll
            for (int r = 0; r < TI; ++r)
                red[r][j] = fmax(red[r][j], red[r][j + off]);
        }
        __syncthreads();
    }

    const float2* gu2 = (const float2*)gu;
    #pragma unroll
    for (int r = 0; r < TI; ++r) {
        double emax = red[r][0];
        double p = ed[r] / (emax + 1e-8);
        if (i0 + r == j) p = p + 1.0;      // + eye
        p *= 0.99;
        double logits = log(p + 1e-8) - log((1.0 - p) + 1e-8);

        float2 u2 = gu2[((size_t)(b * CB + i0 + r)) * CB + j];
        double g0 = -log(-log((double)u2.x + 1e-20) + 1e-20);
        double g1 = -log(-log((double)u2.y + 1e-20) + 1e-20);

        // forward straight-through sample = one_hot(argmax); tie -> index 0
        out[((size_t)(b * CB + i0 + r)) * CB + j] =
            (logits + g0 >= -logits + g1) ? 1.0f : 0.0f;
    }
}

// ---------------------------------------------------------------------------
extern "C" void kernel_launch(void* const* d_in, const int* in_sizes, int n_in,
                              void* d_out, int out_size, void* d_ws, size_t ws_size,
                              hipStream_t stream) {
    const float* x  = (const float*)d_in[0];   // (16,128,512)
    const float* A  = (const float*)d_in[1];   // (257,257)
    const float* gu = (const float*)d_in[2];   // (16,128,128,2)
    float* out = (float*)d_out;                // (16,1,128,128)

    char* ws = (char*)d_ws;
    size_t o = 0;
    double2* tw = (double2*)(ws + o); o += 4096;                       // 4 KB
    float*   At = (float*)(ws + o);   o += ((size_t)FB * FB * 4 + 511) / 512 * 512;  // 264 KB
    double*  xf = (double*)(ws + o);  o += (size_t)NROW * FB * 8;      // 4.21 MB
    double*  Z  = (double*)(ws + o);  o += (size_t)NROW * FB * 8;      // 4.21 MB
    double*  Zt = (double*)(ws + o);  o += (size_t)16 * FB * CB * 8;   // 4.21 MB

    hipLaunchKernelGGL(k_twiddle,   dim3(1),          dim3(256), 0, stream, tw);
    hipLaunchKernelGGL(k_transpose, dim3((FB*FB+255)/256), dim3(256), 0, stream, A, At);
    hipLaunchKernelGGL(k_fft_mag,   dim3(NROW),       dim3(64),  0, stream, x, tw, xf);
    hipLaunchKernelGGL(k_zmat,      dim3(NROW / RT),  dim3(320), 0, stream, xf, At, Z, Zt);
    hipLaunchKernelGGL(k_mask,      dim3(256),        dim3(128), 0, stream, Z, Zt, gu, out);
}

// Round 3
// 81.440 us; speedup vs baseline: 1.6740x; 1.4383x over previous
//
#include <hip/hip_runtime.h>

// Problem sizes
#define LN   512      // FFT length
#define FB   257      // rfft bins = L/2+1
#define CB   128      // channels
#define NROW 2048     // B*C rows
#define RT   8        // rows per k_zmat block
#define TI   8        // i-rows per fallback k_mask block
#define GC   8        // g-chunks in k_dist (7x32 + 1x33)

// ---------------------------------------------------------------------------
// Kernel 0a: twiddle table tw[j] = exp(-2*pi*i*j/512), j=0..255, double.
// ---------------------------------------------------------------------------
__global__ void k_twiddle(double2* __restrict__ tw) {
    int j = threadIdx.x;  // 256 threads
    const double PI = 3.14159265358979323846264338327950288;
    double theta = -2.0 * PI * (double)j / 512.0;
    double s, c;
    sincos(theta, &s, &c);
    tw[j] = make_double2(c, s);
}

// ---------------------------------------------------------------------------
// Kernel 0b: At[f][g] = A[g][f]
// ---------------------------------------------------------------------------
__global__ void k_transpose(const float* __restrict__ A, float* __restrict__ At) {
    int idx = blockIdx.x * 256 + threadIdx.x;
    if (idx < FB * FB) {
        int f = idx / FB;
        int g = idx - f * FB;
        At[idx] = A[g * FB + f];
    }
}

// ---------------------------------------------------------------------------
// Kernel 1: per-row 512-point complex FFT (imag=0), radix-2 DIT in LDS.
// ---------------------------------------------------------------------------
__global__ void k_fft_mag(const float* __restrict__ x,
                          const double2* __restrict__ twg,
                          double* __restrict__ xf) {
    __shared__ double2 a[LN];
    __shared__ double2 tw[256];
    const int row  = blockIdx.x;
    const int lane = threadIdx.x;  // 0..63

    for (int t = lane; t < 256; t += 64) tw[t] = twg[t];

    const float* xr = x + (size_t)row * LN;
    #pragma unroll
    for (int q = 0; q < 8; ++q) {
        int n = lane + 64 * q;
        int r = (int)(__brev((unsigned)n) >> 23);  // 9-bit reverse
        a[r] = make_double2((double)xr[n], 0.0);
    }
    __syncthreads();

    for (int s = 1; s <= 9; ++s) {
        const int half   = 1 << (s - 1);
        const int tshift = 9 - s;
        #pragma unroll
        for (int t = lane; t < 256; t += 64) {
            int k   = t & (half - 1);
            int grp = t >> (s - 1);
            int p0  = (grp << s) + k;
            int p1  = p0 + half;
            double2 w = tw[k << tshift];
            double2 u = a[p0];
            double2 v = a[p1];
            double vr = v.x * w.x - v.y * w.y;
            double vi = v.x * w.y + v.y * w.x;
            a[p0] = make_double2(u.x + vr, u.y + vi);
            a[p1] = make_double2(u.x - vr, u.y - vi);
        }
        __syncthreads();
    }

    for (int k = lane; k < FB; k += 64) {
        double re = a[k].x, im = a[k].y;
        xf[(size_t)row * FB + k] = sqrt(re * re + im * im);
    }
}

// ---------------------------------------------------------------------------
// Kernel 2: Z[row][g] = sum_f xf[row][f] * A[g][f], 8 rows per block.
// Writes row-major Z and per-b transposed Zt[b][g][i].
// ---------------------------------------------------------------------------
__global__ __launch_bounds__(320)
void k_zmat(const double* __restrict__ xf,
            const float* __restrict__ At,
            double* __restrict__ Z,
            double* __restrict__ Zt) {
    __shared__ double sxf[RT][FB];
    const int r0 = blockIdx.x * RT;
    const int t  = threadIdx.x;

    for (int idx = t; idx < RT * FB; idx += 320) {
        int r = idx / FB;
        int f = idx - r * FB;
        sxf[r][f] = xf[(size_t)(r0 + r) * FB + f];
    }
    __syncthreads();

    if (t < FB) {
        const int g = t;
        double acc[RT];
        #pragma unroll
        for (int r = 0; r < RT; ++r) acc[r] = 0.0;

        int f = 0;
        for (; f + 2 <= 256; f += 2) {
            double a0 = (double)At[(size_t)f * FB + g];
            double a1 = (double)At[(size_t)(f + 1) * FB + g];
            #pragma unroll
            for (int r = 0; r < RT; ++r) {
                acc[r] += sxf[r][f] * a0;
                acc[r] += sxf[r][f + 1] * a1;
            }
        }
        {
            double a0 = (double)At[(size_t)256 * FB + g];
            #pragma unroll
            for (int r = 0; r < RT; ++r) acc[r] += sxf[r][256] * a0;
        }

        const int b  = r0 >> 7;
        const int i0 = r0 & (CB - 1);
        #pragma unroll
        for (int r = 0; r < RT; ++r) {
            Z[(size_t)(r0 + r) * FB + g] = acc[r];
            Zt[((size_t)b * FB + g) * CB + (i0 + r)] = acc[r];
        }
    }
}

// ---------------------------------------------------------------------------
// Kernel 3a: partial distances.
// Grid: 16 b x 4 ti x 2 tj x 8 chunks = 1024 blocks, 256 threads.
// Block computes a 32(i) x 64(j) tile over one g-chunk (32 or 33 g).
// g-major LDS panels; 2x4 register micro-tile; b128 reads conflict-free.
// distp[c][b][i][j] += partial sum over chunk c.
// ---------------------------------------------------------------------------
__global__ __launch_bounds__(256)
void k_dist(const double* __restrict__ Zt, double* __restrict__ distp) {
    __shared__ double siT[33][34];   // [gg][ii]  row 272B (16B aligned)
    __shared__ double sjT[33][66];   // [gg][jj]  row 528B (16B aligned)
    const int blk = blockIdx.x;
    const int c   = blk & 7;
    const int tj  = (blk >> 3) & 1;
    const int ti  = (blk >> 4) & 3;
    const int b   = blk >> 6;
    const int g0  = c * 32;
    const int gn  = (c == 7) ? 33 : 32;
    const int i0  = ti * 32;
    const int j0  = tj * 64;
    const double* Zb = Zt + (size_t)b * FB * CB;
    const int tid = threadIdx.x;

    for (int idx = tid; idx < gn * 32; idx += 256) {
        int gg = idx >> 5, ii = idx & 31;
        siT[gg][ii] = Zb[(size_t)(g0 + gg) * CB + i0 + ii];
    }
    for (int idx = tid; idx < gn * 64; idx += 256) {
        int gg = idx >> 6, jj = idx & 63;
        sjT[gg][jj] = Zb[(size_t)(g0 + gg) * CB + j0 + jj];
    }
    __syncthreads();

    const int it = tid >> 4;     // 0..15
    const int jt = tid & 15;     // 0..15
    const int i2 = it * 2;
    const int j4 = jt * 4;

    double acc[2][4];
    #pragma unroll
    for (int r = 0; r < 2; ++r)
        #pragma unroll
        for (int q = 0; q < 4; ++q) acc[r][q] = 0.0;

    int gg = 0;
    for (; gg + 2 <= gn; gg += 2) {
        double2 a0  = *(const double2*)&siT[gg][i2];
        double2 a1  = *(const double2*)&siT[gg + 1][i2];
        double2 b00 = *(const double2*)&sjT[gg][j4];
        double2 b01 = *(const double2*)&sjT[gg][j4 + 2];
        double2 b10 = *(const double2*)&sjT[gg + 1][j4];
        double2 b11 = *(const double2*)&sjT[gg + 1][j4 + 2];
        double e;
        // g = gg
        e = a0.x - b00.x; acc[0][0] += e * e;
        e = a0.x - b00.y; acc[0][1] += e * e;
        e = a0.x - b01.x; acc[0][2] += e * e;
        e = a0.x - b01.y; acc[0][3] += e * e;
        e = a0.y - b00.x; acc[1][0] += e * e;
        e = a0.y - b00.y; acc[1][1] += e * e;
        e = a0.y - b01.x; acc[1][2] += e * e;
        e = a0.y - b01.y; acc[1][3] += e * e;
        // g = gg+1
        e = a1.x - b10.x; acc[0][0] += e * e;
        e = a1.x - b10.y; acc[0][1] += e * e;
        e = a1.x - b11.x; acc[0][2] += e * e;
        e = a1.x - b11.y; acc[0][3] += e * e;
        e = a1.y - b10.x; acc[1][0] += e * e;
        e = a1.y - b10.y; acc[1][1] += e * e;
        e = a1.y - b11.x; acc[1][2] += e * e;
        e = a1.y - b11.y; acc[1][3] += e * e;
    }
    if (gg < gn) {  // odd tail (chunk 7)
        double2 a0  = *(const double2*)&siT[gg][i2];
        double2 b00 = *(const double2*)&sjT[gg][j4];
        double2 b01 = *(const double2*)&sjT[gg][j4 + 2];
        double e;
        e = a0.x - b00.x; acc[0][0] += e * e;
        e = a0.x - b00.y; acc[0][1] += e * e;
        e = a0.x - b01.x; acc[0][2] += e * e;
        e = a0.x - b01.y; acc[0][3] += e * e;
        e = a0.y - b00.x; acc[1][0] += e * e;
        e = a0.y - b00.y; acc[1][1] += e * e;
        e = a0.y - b01.x; acc[1][2] += e * e;
        e = a0.y - b01.y; acc[1][3] += e * e;
    }

    double* dp = distp + (((size_t)c * 16 + b) * CB + (i0 + i2)) * CB + (j0 + j4);
    #pragma unroll
    for (int r = 0; r < 2; ++r) {
        dp[r * CB + 0] = acc[r][0];
        dp[r * CB + 1] = acc[r][1];
        dp[r * CB + 2] = acc[r][2];
        dp[r * CB + 3] = acc[r][3];
    }
}

// ---------------------------------------------------------------------------
// Kernel 3b: combine partials, rowmax, logits, gumbel compare -> mask.
// Grid: 2048 blocks ((b,i)), 128 threads (j).
// ---------------------------------------------------------------------------
__global__ __launch_bounds__(128)
void k_mask2(const double* __restrict__ distp,
             const float* __restrict__ gu,
             float* __restrict__ out) {
    __shared__ double wmax[2];
    const int bi = blockIdx.x;       // b*128 + i
    const int i  = bi & (CB - 1);
    const int b  = bi >> 7;
    const int j  = threadIdx.x;      // 0..127

    const size_t sc   = (size_t)16 * CB * CB;
    const size_t base = ((size_t)b * CB + i) * CB + j;
    double s = 0.0;
    #pragma unroll
    for (int c = 0; c < GC; ++c) s += distp[base + (size_t)c * sc];

    double ed = 1.0 / (s + 3e-8);
    if (j == i) ed = 0.0;            // * (1 - eye)

    // max over 128: wave shuffle (64) + cross-wave LDS
    double m = ed;
    #pragma unroll
    for (int off = 32; off >= 1; off >>= 1)
        m = fmax(m, __shfl_xor(m, off, 64));
    if ((j & 63) == 0) wmax[j >> 6] = m;
    __syncthreads();
    double emax = fmax(wmax[0], wmax[1]);

    double p = ed / (emax + 1e-8);
    if (j == i) p = p + 1.0;         // + eye
    p *= 0.99;
    double logits = log(p + 1e-8) - log((1.0 - p) + 1e-8);

    float2 u2 = ((const float2*)gu)[(size_t)bi * CB + j];
    double g0 = -log(-log((double)u2.x + 1e-20) + 1e-20);
    double g1 = -log(-log((double)u2.y + 1e-20) + 1e-20);

    out[(size_t)bi * CB + j] = (logits + g0 >= -logits + g1) ? 1.0f : 0.0f;
}

// ---------------------------------------------------------------------------
// Fallback kernel (round-2 k_mask) in case ws_size is too small for distp.
// ---------------------------------------------------------------------------
__global__ __launch_bounds__(128)
void k_mask(const double* __restrict__ Z,
            const double* __restrict__ Zt,
            const float* __restrict__ gu,
            float* __restrict__ out) {
    __shared__ double zi[TI][FB];
    __shared__ double red[TI][CB];
    const int blk = blockIdx.x;
    const int b   = blk >> 4;
    const int i0  = (blk & 15) * TI;
    const int j   = threadIdx.x;

    for (int idx = j; idx < TI * FB; idx += CB) {
        int r = idx / FB;
        int f = idx - r * FB;
        zi[r][f] = Z[((size_t)(b * CB + i0 + r)) * FB + f];
    }
    __syncthreads();

    const double* Ztb = Zt + (size_t)b * FB * CB;
    double acc[TI];
    #pragma unroll
    for (int r = 0; r < TI; ++r) acc[r] = 0.0;

    int g = 0;
    for (; g + 2 <= 256; g += 2) {
        double z0 = Ztb[(size_t)g * CB + j];
        double z1 = Ztb[(size_t)(g + 1) * CB + j];
        #pragma unroll
        for (int r = 0; r < TI; ++r) {
            double e0 = z0 - zi[r][g];
            acc[r] += e0 * e0;
            double e1 = z1 - zi[r][g + 1];
            acc[r] += e1 * e1;
        }
    }
    {
        double z0 = Ztb[(size_t)256 * CB + j];
        #pragma unroll
        for (int r = 0; r < TI; ++r) {
            double e0 = z0 - zi[r][256];
            acc[r] += e0 * e0;
        }
    }

    double ed[TI];
    #pragma unroll
    for (int r = 0; r < TI; ++r) {
        ed[r] = 1.0 / (acc[r] + 3e-8);
        if (i0 + r == j) ed[r] = 0.0;
        red[r][j] = ed[r];
    }
    __syncthreads();

    #pragma unroll
    for (int off = 64; off >= 1; off >>= 1) {
        if (j < off) {
            #pragma unroll
            for (int r = 0; r < TI; ++r)
                red[r][j] = fmax(red[r][j], red[r][j + off]);
        }
        __syncthreads();
    }

    const float2* gu2 = (const float2*)gu;
    #pragma unroll
    for (int r = 0; r < TI; ++r) {
        double emax = red[r][0];
        double p = ed[r] / (emax + 1e-8);
        if (i0 + r == j) p = p + 1.0;
        p *= 0.99;
        double logits = log(p + 1e-8) - log((1.0 - p) + 1e-8);

        float2 u2 = gu2[((size_t)(b * CB + i0 + r)) * CB + j];
        double g0 = -log(-log((double)u2.x + 1e-20) + 1e-20);
        double g1 = -log(-log((double)u2.y + 1e-20) + 1e-20);

        out[((size_t)(b * CB + i0 + r)) * CB + j] =
            (logits + g0 >= -logits + g1) ? 1.0f : 0.0f;
    }
}

// ---------------------------------------------------------------------------
extern "C" void kernel_launch(void* const* d_in, const int* in_sizes, int n_in,
                              void* d_out, int out_size, void* d_ws, size_t ws_size,
                              hipStream_t stream) {
    const float* x  = (const float*)d_in[0];   // (16,128,512)
    const float* A  = (const float*)d_in[1];   // (257,257)
    const float* gu = (const float*)d_in[2];   // (16,128,128,2)
    float* out = (float*)d_out;                // (16,1,128,128)

    char* ws = (char*)d_ws;
    size_t o = 0;
    double2* tw = (double2*)(ws + o); o += 4096;
    float*   At = (float*)(ws + o);   o += ((size_t)FB * FB * 4 + 511) / 512 * 512;
    double*  xf = (double*)(ws + o);  o += (size_t)NROW * FB * 8;
    double*  Z  = (double*)(ws + o);  o += (size_t)NROW * FB * 8;
    double*  Zt = (double*)(ws + o);  o += (size_t)16 * FB * CB * 8;
    double*  dp = (double*)(ws + o);  o += (size_t)GC * 16 * CB * CB * 8;  // 16.8 MB
    const size_t need_fast = o;

    hipLaunchKernelGGL(k_twiddle,   dim3(1),               dim3(256), 0, stream, tw);
    hipLaunchKernelGGL(k_transpose, dim3((FB*FB+255)/256), dim3(256), 0, stream, A, At);
    hipLaunchKernelGGL(k_fft_mag,   dim3(NROW),            dim3(64),  0, stream, x, tw, xf);
    hipLaunchKernelGGL(k_zmat,      dim3(NROW / RT),       dim3(320), 0, stream, xf, At, Z, Zt);

    if (ws_size >= need_fast) {
        hipLaunchKernelGGL(k_dist,  dim3(1024), dim3(256), 0, stream, Zt, dp);
        hipLaunchKernelGGL(k_mask2, dim3(NROW), dim3(128), 0, stream, dp, gu, out);
    } else {
        hipLaunchKernelGGL(k_mask,  dim3(256),  dim3(128), 0, stream, Z, Zt, gu, out);
    }
}

// Round 4
// 66.947 us; speedup vs baseline: 2.0364x; 1.2165x over previous
//
#include <hip/hip_runtime.h>

// Problem sizes
#define LN   512      // FFT length
#define FB   257      // rfft bins = L/2+1
#define CB   128      // channels
#define NROW 2048     // B*C rows
#define RT   4        // rows per k_zmat block
#define GC   8        // g-chunks in k_dist (7x32 + 1x33)

// ---------------------------------------------------------------------------
// Kernel 0: prep — At[f][g] = A[g][f] (blocks 0..258) + twiddles (block 259).
// ---------------------------------------------------------------------------
__global__ void k_prep(const float* __restrict__ A, float* __restrict__ At,
                       double2* __restrict__ tw) {
    if (blockIdx.x < 259) {
        int idx = blockIdx.x * 256 + threadIdx.x;
        if (idx < FB * FB) {
            int f = idx / FB;
            int g = idx - f * FB;
            At[idx] = A[g * FB + f];
        }
    } else {
        int j = threadIdx.x;  // 0..255
        const double PI = 3.14159265358979323846264338327950288;
        double theta = -2.0 * PI * (double)j / 512.0;
        double s, c;
        sincos(theta, &s, &c);
        tw[j] = make_double2(c, s);
    }
}

// ---------------------------------------------------------------------------
// Kernel 1: paired real FFT — one complex-512 FFT per TWO input rows
// (x_r0 + i*x_r1), radix-2 DIT in LDS, then unpack both spectra magnitudes.
// 1024 blocks x 128 threads.
// ---------------------------------------------------------------------------
__global__ __launch_bounds__(128)
void k_fft2(const float* __restrict__ x,
            const double2* __restrict__ twg,
            double* __restrict__ xf) {
    __shared__ double2 a[LN];
    __shared__ double2 tw[256];
    const int pair = blockIdx.x;          // 0..1023
    const int tid  = threadIdx.x;         // 0..127
    const int r0   = pair * 2;
    const int r1   = r0 + 1;

    for (int t = tid; t < 256; t += 128) tw[t] = twg[t];

    const float* x0 = x + (size_t)r0 * LN;
    const float* x1 = x + (size_t)r1 * LN;
    #pragma unroll
    for (int q = 0; q < 4; ++q) {
        int n = tid + 128 * q;
        int r = (int)(__brev((unsigned)n) >> 23);  // 9-bit reverse
        a[r] = make_double2((double)x0[n], (double)x1[n]);
    }
    __syncthreads();

    for (int s = 1; s <= 9; ++s) {
        const int half   = 1 << (s - 1);
        const int tshift = 9 - s;
        #pragma unroll
        for (int u = 0; u < 2; ++u) {
            int t   = tid + 128 * u;
            int k   = t & (half - 1);
            int grp = t >> (s - 1);
            int p0  = (grp << s) + k;
            int p1  = p0 + half;
            double2 w  = tw[k << tshift];
            double2 uu = a[p0];
            double2 v  = a[p1];
            double vr = v.x * w.x - v.y * w.y;
            double vi = v.x * w.y + v.y * w.x;
            a[p0] = make_double2(uu.x + vr, uu.y + vi);
            a[p1] = make_double2(uu.x - vr, uu.y - vi);
        }
        __syncthreads();
    }

    // unpack: X_k = (Z_k + conj(Z_{N-k}))/2 ; Y_k = (Z_k - conj(Z_{N-k}))/(2i)
    double* xf0 = xf + (size_t)r0 * FB;
    double* xf1 = xf + (size_t)r1 * FB;
    for (int k = tid; k < FB; k += 128) {
        int m = (LN - k) & (LN - 1);
        double2 zk = a[k];
        double2 zm = a[m];
        double xr = 0.5 * (zk.x + zm.x);
        double xi = 0.5 * (zk.y - zm.y);
        double yr = 0.5 * (zk.y + zm.y);
        double yi = 0.5 * (zm.x - zk.x);
        xf0[k] = sqrt(xr * xr + xi * xi);
        xf1[k] = sqrt(yr * yr + yi * yi);
    }
}

// ---------------------------------------------------------------------------
// Kernel 2: Zt[b][g][i] = sum_f xf[b,i][f] * A[g][f], 4 rows per block.
// 512 blocks x 320 threads (thread = g), f-loop unrolled x4.
// ---------------------------------------------------------------------------
__global__ __launch_bounds__(320)
void k_zmat(const double* __restrict__ xf,
            const float* __restrict__ At,
            double* __restrict__ Zt) {
    __shared__ double sxf[RT][FB];
    const int r0 = blockIdx.x * RT;
    const int t  = threadIdx.x;

    for (int idx = t; idx < RT * FB; idx += 320) {
        int r = idx / FB;
        int f = idx - r * FB;
        sxf[r][f] = xf[(size_t)(r0 + r) * FB + f];
    }
    __syncthreads();

    if (t < FB) {
        const int g = t;
        const float* Ag = At + g;
        double acc[RT];
        #pragma unroll
        for (int r = 0; r < RT; ++r) acc[r] = 0.0;

        int f = 0;
        for (; f + 4 <= 256; f += 4) {
            double a0 = (double)Ag[(size_t)f * FB];
            double a1 = (double)Ag[(size_t)(f + 1) * FB];
            double a2 = (double)Ag[(size_t)(f + 2) * FB];
            double a3 = (double)Ag[(size_t)(f + 3) * FB];
            #pragma unroll
            for (int r = 0; r < RT; ++r)
                acc[r] += sxf[r][f] * a0 + sxf[r][f + 1] * a1 +
                          sxf[r][f + 2] * a2 + sxf[r][f + 3] * a3;
        }
        {   // f = 256 tail
            double a0 = (double)Ag[(size_t)256 * FB];
            #pragma unroll
            for (int r = 0; r < RT; ++r) acc[r] += sxf[r][256] * a0;
        }

        const int b  = r0 >> 7;
        const int i0 = r0 & (CB - 1);
        #pragma unroll
        for (int r = 0; r < RT; ++r)
            Zt[((size_t)b * FB + g) * CB + (i0 + r)] = acc[r];
    }
}

// ---------------------------------------------------------------------------
// Kernel 3a: partial distances.
// Grid: 16 b x 4 ti x 2 tj x 8 chunks = 1024 blocks, 256 threads.
// Block computes a 32(i) x 64(j) tile over one g-chunk (32 or 33 g).
// ---------------------------------------------------------------------------
__global__ __launch_bounds__(256)
void k_dist(const double* __restrict__ Zt, double* __restrict__ distp) {
    __shared__ double siT[33][34];   // [gg][ii]
    __shared__ double sjT[33][66];   // [gg][jj]
    const int blk = blockIdx.x;
    const int c   = blk & 7;
    const int tj  = (blk >> 3) & 1;
    const int ti  = (blk >> 4) & 3;
    const int b   = blk >> 6;
    const int g0  = c * 32;
    const int gn  = (c == 7) ? 33 : 32;
    const int i0  = ti * 32;
    const int j0  = tj * 64;
    const double* Zb = Zt + (size_t)b * FB * CB;
    const int tid = threadIdx.x;

    for (int idx = tid; idx < gn * 32; idx += 256) {
        int gg = idx >> 5, ii = idx & 31;
        siT[gg][ii] = Zb[(size_t)(g0 + gg) * CB + i0 + ii];
    }
    for (int idx = tid; idx < gn * 64; idx += 256) {
        int gg = idx >> 6, jj = idx & 63;
        sjT[gg][jj] = Zb[(size_t)(g0 + gg) * CB + j0 + jj];
    }
    __syncthreads();

    const int it = tid >> 4;     // 0..15
    const int jt = tid & 15;     // 0..15
    const int i2 = it * 2;
    const int j4 = jt * 4;

    double acc[2][4];
    #pragma unroll
    for (int r = 0; r < 2; ++r)
        #pragma unroll
        for (int q = 0; q < 4; ++q) acc[r][q] = 0.0;

    int gg = 0;
    for (; gg + 2 <= gn; gg += 2) {
        double2 a0  = *(const double2*)&siT[gg][i2];
        double2 a1  = *(const double2*)&siT[gg + 1][i2];
        double2 b00 = *(const double2*)&sjT[gg][j4];
        double2 b01 = *(const double2*)&sjT[gg][j4 + 2];
        double2 b10 = *(const double2*)&sjT[gg + 1][j4];
        double2 b11 = *(const double2*)&sjT[gg + 1][j4 + 2];
        double e;
        e = a0.x - b00.x; acc[0][0] += e * e;
        e = a0.x - b00.y; acc[0][1] += e * e;
        e = a0.x - b01.x; acc[0][2] += e * e;
        e = a0.x - b01.y; acc[0][3] += e * e;
        e = a0.y - b00.x; acc[1][0] += e * e;
        e = a0.y - b00.y; acc[1][1] += e * e;
        e = a0.y - b01.x; acc[1][2] += e * e;
        e = a0.y - b01.y; acc[1][3] += e * e;
        e = a1.x - b10.x; acc[0][0] += e * e;
        e = a1.x - b10.y; acc[0][1] += e * e;
        e = a1.x - b11.x; acc[0][2] += e * e;
        e = a1.x - b11.y; acc[0][3] += e * e;
        e = a1.y - b10.x; acc[1][0] += e * e;
        e = a1.y - b10.y; acc[1][1] += e * e;
        e = a1.y - b11.x; acc[1][2] += e * e;
        e = a1.y - b11.y; acc[1][3] += e * e;
    }
    if (gg < gn) {  // odd tail (chunk 7)
        double2 a0  = *(const double2*)&siT[gg][i2];
        double2 b00 = *(const double2*)&sjT[gg][j4];
        double2 b01 = *(const double2*)&sjT[gg][j4 + 2];
        double e;
        e = a0.x - b00.x; acc[0][0] += e * e;
        e = a0.x - b00.y; acc[0][1] += e * e;
        e = a0.x - b01.x; acc[0][2] += e * e;
        e = a0.x - b01.y; acc[0][3] += e * e;
        e = a0.y - b00.x; acc[1][0] += e * e;
        e = a0.y - b00.y; acc[1][1] += e * e;
        e = a0.y - b01.x; acc[1][2] += e * e;
        e = a0.y - b01.y; acc[1][3] += e * e;
    }

    double* dp = distp + (((size_t)c * 16 + b) * CB + (i0 + i2)) * CB + (j0 + j4);
    #pragma unroll
    for (int r = 0; r < 2; ++r) {
        dp[r * CB + 0] = acc[r][0];
        dp[r * CB + 1] = acc[r][1];
        dp[r * CB + 2] = acc[r][2];
        dp[r * CB + 3] = acc[r][3];
    }
}

// ---------------------------------------------------------------------------
// Kernel 3b: combine partials, rowmax, logits, gumbel compare -> mask.
// ---------------------------------------------------------------------------
__global__ __launch_bounds__(128)
void k_mask2(const double* __restrict__ distp,
             const float* __restrict__ gu,
             float* __restrict__ out) {
    __shared__ double wmax[2];
    const int bi = blockIdx.x;       // b*128 + i
    const int i  = bi & (CB - 1);
    const int b  = bi >> 7;
    const int j  = threadIdx.x;      // 0..127

    const size_t sc   = (size_t)16 * CB * CB;
    const size_t base = ((size_t)b * CB + i) * CB + j;
    double s = 0.0;
    #pragma unroll
    for (int c = 0; c < GC; ++c) s += distp[base + (size_t)c * sc];

    double ed = 1.0 / (s + 3e-8);
    if (j == i) ed = 0.0;            // * (1 - eye)

    double m = ed;
    #pragma unroll
    for (int off = 32; off >= 1; off >>= 1)
        m = fmax(m, __shfl_xor(m, off, 64));
    if ((j & 63) == 0) wmax[j >> 6] = m;
    __syncthreads();
    double emax = fmax(wmax[0], wmax[1]);

    double p = ed / (emax + 1e-8);
    if (j == i) p = p + 1.0;         // + eye
    p *= 0.99;
    double logits = log(p + 1e-8) - log((1.0 - p) + 1e-8);

    float2 u2 = ((const float2*)gu)[(size_t)bi * CB + j];
    double g0 = -log(-log((double)u2.x + 1e-20) + 1e-20);
    double g1 = -log(-log((double)u2.y + 1e-20) + 1e-20);

    out[(size_t)bi * CB + j] = (logits + g0 >= -logits + g1) ? 1.0f : 0.0f;
}

// ---------------------------------------------------------------------------
extern "C" void kernel_launch(void* const* d_in, const int* in_sizes, int n_in,
                              void* d_out, int out_size, void* d_ws, size_t ws_size,
                              hipStream_t stream) {
    const float* x  = (const float*)d_in[0];   // (16,128,512)
    const float* A  = (const float*)d_in[1];   // (257,257)
    const float* gu = (const float*)d_in[2];   // (16,128,128,2)
    float* out = (float*)d_out;                // (16,1,128,128)

    char* ws = (char*)d_ws;
    size_t o = 0;
    double2* tw = (double2*)(ws + o); o += 4096;
    float*   At = (float*)(ws + o);   o += ((size_t)FB * FB * 4 + 511) / 512 * 512;
    double*  xf = (double*)(ws + o);  o += (size_t)NROW * FB * 8;      // 4.21 MB
    double*  Zt = (double*)(ws + o);  o += (size_t)16 * FB * CB * 8;   // 4.21 MB
    double*  dp = (double*)(ws + o);  o += (size_t)GC * 16 * CB * CB * 8;  // 16.8 MB

    hipLaunchKernelGGL(k_prep,  dim3(260),       dim3(256), 0, stream, A, At, tw);
    hipLaunchKernelGGL(k_fft2,  dim3(NROW / 2),  dim3(128), 0, stream, x, tw, xf);
    hipLaunchKernelGGL(k_zmat,  dim3(NROW / RT), dim3(320), 0, stream, xf, At, Zt);
    hipLaunchKernelGGL(k_dist,  dim3(1024),      dim3(256), 0, stream, Zt, dp);
    hipLaunchKernelGGL(k_mask2, dim3(NROW),      dim3(128), 0, stream, dp, gu, out);
}